// Round 9
// baseline (258.158 us; speedup 1.0000x reference)
//
#include <hip/hip_runtime.h>
#include <hip/hip_fp16.h>
#include <cstdint>

// Fisher-Kolmogorov explicit Euler, B=2, 128^3, up to 30 masked micro-steps
// (delta_t_days = randint(0,4) -> d <= 3 -> steps <= 30).
// Round-18 = Round-17 resubmitted verbatim (R17 bench was an infra failure:
// "MI355X container failed twice" — kernel never measured).
//  Theory (unfalsified): per-STEP cost pinned at ~7.7us across 2/3-step
//  fusion, occupancy 8/12/16 waves, 2/3/16 barriers, XCD swizzle -> the
//  invariant is TCC-level bytes/step: u-rd 16.8 + dr 16.8 + u-wr 16.8
//  ~ 50MB at ~3TB/s stencil-effective BW. This round halves u-state bytes:
//  ping-pong buffers are fp16 (arithmetic fp32; u0/Dm/Rm reads and final
//  `out` write stay f32). dr stays packed bf16 (4B/cell).
//  Precision: u in [0,1], fp16 round-trip err <= 5e-4/store, <=29 stores,
//  near-unity Jacobian -> ~+3e-3 vs threshold 2e-2 (current 3.9e-3).
//  Kernel templated on FIRST: launch 0 reads f32 u0, later read fp16.
//  Structure otherwise byte-identical to R16 (XCD z-slab swizzle kept).

constexpr int NX = 128, NY = 128, NZ = 128;
constexpr int PLANE = NX * NY;            // 16384
constexpr int VOL   = NZ * PLANE;         // 2,097,152
constexpr int TOTAL = 2 * VOL;            // 4,194,304
constexpr float DT  = 0.1f;               // MICRO_DT
constexpr int MAX_TRIPLES = 10;           // 30 steps / 3

constexpr int TY = 8, TZ = 4;             // block interior tile (x full 128)
constexpr int S1Z = TZ + 4, S1Y = TY + 4; // step-1 region: 8 z x 12 y (48 KB)
constexpr int S2Z = TZ + 2, S2Y = TY + 2; // step-2 region: 6 z x 10 y (aliased)
constexpr int BLOCKS = 2 * (NZ / TZ) * (NY / TY);  // 2*32*16 = 1024

__device__ __forceinline__ float4 ld4(const float* p) { return *(const float4*)p; }

__device__ __forceinline__ float4 ld4h(const __half* p) {
    uint2 raw = *(const uint2*)p;                  // 8B load
    __half2 lo = *(__half2*)&raw.x, hi = *(__half2*)&raw.y;
    float2 a = __half22float2(lo), b = __half22float2(hi);
    return make_float4(a.x, a.y, b.x, b.y);
}
__device__ __forceinline__ void st4h(__half* p, float4 v) {
    __half2 lo = __floats2half2_rn(v.x, v.y);
    __half2 hi = __floats2half2_rn(v.z, v.w);
    uint2 pack = make_uint2(*(uint32_t*)&lo, *(uint32_t*)&hi);
    *(uint2*)p = pack;                             // 8B store
}

__device__ __forceinline__ uint32_t f2bf(float f) {
    uint32_t u = __float_as_uint(f);
    u += 0x7fffu + ((u >> 16) & 1u);      // round-to-nearest-even
    return u >> 16;
}
__device__ __forceinline__ float bf_lo(uint32_t p) { return __uint_as_float(p << 16); }
__device__ __forceinline__ float bf_hi(uint32_t p) { return __uint_as_float(p & 0xffff0000u); }
__device__ __forceinline__ float clip01(float v) { return fminf(fmaxf(v, 0.0f), 1.0f); }

__device__ __forceinline__ float4 fkstep(float dt, float4 c, float xm, float xp,
                                         float4 ym, float4 yp,
                                         float4 zm, float4 zp,
                                         float4 Dv, float4 Rv) {
    float4 o;
    o.x = fmaf(dt, fmaf(Dv.x, (xm + c.y) + (ym.x + yp.x) + (zm.x + zp.x) - 6.0f * c.x,
                        Rv.x * c.x * (1.0f - c.x)), c.x);
    o.y = fmaf(dt, fmaf(Dv.y, (c.x + c.z) + (ym.y + yp.y) + (zm.y + zp.y) - 6.0f * c.y,
                        Rv.y * c.y * (1.0f - c.y)), c.y);
    o.z = fmaf(dt, fmaf(Dv.z, (c.y + c.w) + (ym.z + yp.z) + (zm.z + zp.z) - 6.0f * c.z,
                        Rv.z * c.z * (1.0f - c.z)), c.z);
    o.w = fmaf(dt, fmaf(Dv.w, (c.z + xp) + (ym.w + yp.w) + (zm.w + zp.w) - 6.0f * c.w,
                        Rv.w * c.w * (1.0f - c.w)), c.w);
    return o;
}

__device__ __forceinline__ float4 unpackD(uint4 p) {
    return make_float4(bf_lo(p.x), bf_lo(p.y), bf_lo(p.z), bf_lo(p.w));
}
__device__ __forceinline__ float4 unpackR(uint4 p) {
    return make_float4(bf_hi(p.x), bf_hi(p.y), bf_hi(p.z), bf_hi(p.w));
}

template<bool FIRST>
__global__ __launch_bounds__(256, 3)
void fk_triple(const float* __restrict__ srcf, const __half* __restrict__ srch,
               __half* __restrict__ dsth, float* __restrict__ out,
               const float* __restrict__ u0,
               const float* __restrict__ Dm, const float* __restrict__ Rm,
               uint32_t* __restrict__ dr, const int* __restrict__ dtd, int p)
{
    // ---- XCD-slab swizzle: bid%8 selects a contiguous z-slab ----
    const int bid  = blockIdx.x;
    const int slab = bid & 7;                        // XCD key 0..7
    const int rest = bid >> 3;                       // 0..127
    const int b    = rest >> 6;                      // batch item
    const int zw   = (rest >> 4) & 3;                // z tile within slab
    const int yt   = rest & 15;                      // y tile
    const int zb   = slab * 4 + zw;                  // z tile 0..31

    int d = dtd[b]; d = d < 0 ? 0 : (d > 3 ? 3 : d); // randint(0,4) is excl-upper
    const int steps = d * 10;
    const int g0 = 3 * p;                            // first global step of launch

    const int z0 = zb * TZ, y0 = yt * TY;
    const int tid = threadIdx.x;
    const int xq  = tid & 31;                        // float4 lane within row
    const int yi  = tid >> 5;                        // 0..7
    const int baseb = b << 21;
    const float4 zero = make_float4(0.f, 0.f, 0.f, 0.f);

    // typed source access helpers (compile-time pruned)
    auto LDU = [&](int idx) -> float4 {
        if constexpr (FIRST) return ld4(srcf + idx);
        else                 return ld4h(srch + idx);
    };
    auto LDU1 = [&](int idx) -> float {
        if constexpr (FIRST) return srcf[idx];
        else                 return __half2float(srch[idx]);
    };

    if (g0 >= steps) {
        // d==0 items never get a step write: emit clip(u0) once, in launch 0.
        if (steps == 0 && p == 0) {
            #pragma unroll
            for (int k = 0; k < TZ; ++k) {
                const int idx = baseb + (z0 + k) * PLANE + (y0 + yi) * NX + (xq << 2);
                const float4 v = ld4(u0 + idx);
                float4 o;
                o.x = clip01(v.x); o.y = clip01(v.y);
                o.z = clip01(v.z); o.w = clip01(v.w);
                *(float4*)(out + idx) = o;
            }
        }
        return;                                      // block-uniform exit
    }
    const bool last  = (steps - g0 <= 3);
    const float m1 = (g0 + 1 < steps) ? DT : 0.0f;   // sub-step masks (g0 active)
    const float m2 = (g0 + 2 < steps) ? DT : 0.0f;   // fmaf(0,du,u)==u exactly

    __shared__ float s1[S1Z * S1Y * NX];             // 48 KiB; s2 aliases this
    float* const s2b = s1;                           // s2 layout: [S2Z][S2Y][NX]

    uint4 pr[TZ];                                    // packed (D,rho) bf16, interior

    // ---- Phase 1 pass 0: step-1 on interior-y columns of s1, z-rolled over
    // all 8 s1 planes (z0-2 .. z0+5). Captures/publishes interior dr. ----
    {
        const int y = y0 + yi;                       // in-domain by construction
        const int colbase = baseb + y * NX + (xq << 2);
        const bool has_ym = (y > 0), has_yp = (y < NY - 1);
        const bool has_l = (xq > 0), has_r = (xq < 31);
        const int zlo = z0 - 2;

        float4 um = ((unsigned)(zlo - 1) < (unsigned)NZ) ? LDU(colbase + (zlo - 1) * PLANE) : zero;
        float4 uc = ((unsigned)zlo < (unsigned)NZ) ? LDU(colbase + zlo * PLANE) : zero;
        #pragma unroll
        for (int rz = 0; rz < S1Z; ++rz) {
            const int z = zlo + rz;
            const int idx = colbase + z * PLANE;
            const float4 un = ((unsigned)(z + 1) < (unsigned)NZ) ? LDU(idx + PLANE) : zero;
            float4 o = zero;
            if ((unsigned)z < (unsigned)NZ) {
                const float4 ym4 = has_ym ? LDU(idx - NX) : zero;
                const float4 yp4 = has_yp ? LDU(idx + NX) : zero;
                const float xm = has_l ? LDU1(idx - 1) : 0.0f;
                const float xp = has_r ? LDU1(idx + 4) : 0.0f;
                float4 Dv, Rv;
                if constexpr (FIRST) {
                    Dv = ld4(Dm + idx);
                    Rv = ld4(Rm + idx);
                    if (rz >= 2 && rz < 2 + TZ) {    // interior z: publish + keep
                        uint4 pk;
                        pk.x = f2bf(Dv.x) | (f2bf(Rv.x) << 16);
                        pk.y = f2bf(Dv.y) | (f2bf(Rv.y) << 16);
                        pk.z = f2bf(Dv.z) | (f2bf(Rv.z) << 16);
                        pk.w = f2bf(Dv.w) | (f2bf(Rv.w) << 16);
                        *(uint4*)(dr + idx) = pk;
                        pr[rz - 2] = pk;
                    }
                } else {
                    const uint4 pk = *(const uint4*)(dr + idx);
                    Dv = unpackD(pk);
                    Rv = unpackR(pk);
                    if (rz >= 2 && rz < 2 + TZ) pr[rz - 2] = pk;
                }
                o = fkstep(DT, uc, xm, xp, ym4, yp4, um, un, Dv, Rv);
            }
            *(float4*)&s1[(rz * S1Y + (yi + 2)) * NX + (xq << 2)] = o;
            um = uc; uc = un;
        }
    }

    // ---- Phase 1 pass 1: step-1 on the 4 y-halo rows x 8 planes (32 row-
    // tasks, flat over all threads, 4 iterations). ----
    for (int i = tid; i < 32 * 32; i += 256) {
        const int cxq = i & 31;
        const int r   = i >> 5;                      // 0..31
        const int rr  = r >> 3;                      // 0..3
        const int rz  = r & 7;
        const int ry  = (rr < 2) ? rr : rr + 8;      // 0,1,10,11
        const int y = y0 - 2 + ry;
        const int z = z0 - 2 + rz;
        float4 o = zero;                             // out-of-domain -> 0
        if ((unsigned)y < (unsigned)NY && (unsigned)z < (unsigned)NZ) {
            const int idx = baseb + z * PLANE + y * NX + (cxq << 2);
            const float4 c  = LDU(idx);
            const float xm  = (cxq > 0)  ? LDU1(idx - 1) : 0.0f;
            const float xp  = (cxq < 31) ? LDU1(idx + 4) : 0.0f;
            const float4 ym4 = (y > 0)      ? LDU(idx - NX)    : zero;
            const float4 yp4 = (y < NY - 1) ? LDU(idx + NX)    : zero;
            const float4 zm4 = (z > 0)      ? LDU(idx - PLANE) : zero;
            const float4 zp4 = (z < NZ - 1) ? LDU(idx + PLANE) : zero;
            float4 Dv, Rv;
            if constexpr (FIRST) {
                Dv = ld4(Dm + idx);
                Rv = ld4(Rm + idx);
            } else {
                const uint4 pk = *(const uint4*)(dr + idx);
                Dv = unpackD(pk);
                Rv = unpackR(pk);
            }
            o = fkstep(DT, c, xm, xp, ym4, yp4, zm4, zp4, Dv, Rv);
        }
        *(float4*)&s1[(rz * S1Y + ry) * NX + (cxq << 2)] = o;
    }
    __syncthreads();                                 // barrier 1: s1 complete

    // ---- Phase 2 (register-staged): step-2 from s1 into registers ----
    float4 s2i[S2Z];                                 // interior rows, ry2 = yi+1
    {
        const int ry1 = yi + 2;                      // this cell's s1 row
        float4 zmv = *(const float4*)&s1[(0 * S1Y + ry1) * NX + (xq << 2)];
        float4 cv  = *(const float4*)&s1[(1 * S1Y + ry1) * NX + (xq << 2)];
        #pragma unroll
        for (int rz2 = 0; rz2 < S2Z; ++rz2) {
            const int rz1 = rz2 + 1;
            const float4 zpv = *(const float4*)&s1[((rz1 + 1) * S1Y + ry1) * NX + (xq << 2)];
            const int z = z0 - 1 + rz2;
            float4 o = zero;
            if ((unsigned)z < (unsigned)NZ) {
                const float* rowc = &s1[(rz1 * S1Y + ry1) * NX];
                const float xm = (xq > 0)  ? rowc[(xq << 2) - 1] : 0.0f;
                const float xp = (xq < 31) ? rowc[(xq << 2) + 4] : 0.0f;
                const float4 ym4 = *(const float4*)&s1[(rz1 * S1Y + ry1 - 1) * NX + (xq << 2)];
                const float4 yp4 = *(const float4*)&s1[(rz1 * S1Y + ry1 + 1) * NX + (xq << 2)];
                float4 Dv, Rv;
                if (rz2 >= 1 && rz2 < 1 + TZ) {      // interior z: from registers
                    Dv = unpackD(pr[rz2 - 1]);
                    Rv = unpackR(pr[rz2 - 1]);
                } else {                             // z halo planes
                    const int idx = baseb + z * PLANE + (y0 + yi) * NX + (xq << 2);
                    if constexpr (FIRST) {
                        Dv = ld4(Dm + idx);
                        Rv = ld4(Rm + idx);
                    } else {
                        const uint4 pk = *(const uint4*)(dr + idx);
                        Dv = unpackD(pk);
                        Rv = unpackR(pk);
                    }
                }
                o = fkstep(m1, cv, xm, xp, ym4, yp4, zmv, zpv, Dv, Rv);
            }
            s2i[rz2] = o;
            zmv = cv; cv = zpv;
        }
    }

    // y-halo rows of s2: 12 row-tasks x 32 f4 = 384 tasks, staged in regs.
    float4 s2h0 = zero, s2h1 = zero;
    #pragma unroll
    for (int kk = 0; kk < 2; ++kk) {
        const int i = tid + kk * 256;
        if (i < 12 * 32) {
            const int cxq = i & 31;
            const int r   = i >> 5;                  // 0..11
            const int ry2 = (r < 6) ? 0 : 9;
            const int rz2 = (r < 6) ? r : r - 6;
            const int y = y0 - 1 + ry2;
            const int z = z0 - 1 + rz2;
            float4 o = zero;
            if ((unsigned)y < (unsigned)NY && (unsigned)z < (unsigned)NZ) {
                const int rz1 = rz2 + 1, ry1 = ry2 + 1;
                const float* rowc = &s1[(rz1 * S1Y + ry1) * NX];
                const float4 cv = *(const float4*)&rowc[cxq << 2];
                const float xm = (cxq > 0)  ? rowc[(cxq << 2) - 1] : 0.0f;
                const float xp = (cxq < 31) ? rowc[(cxq << 2) + 4] : 0.0f;
                const float4 ym4 = *(const float4*)&s1[(rz1 * S1Y + ry1 - 1) * NX + (cxq << 2)];
                const float4 yp4 = *(const float4*)&s1[(rz1 * S1Y + ry1 + 1) * NX + (cxq << 2)];
                const float4 zm4 = *(const float4*)&s1[((rz1 - 1) * S1Y + ry1) * NX + (cxq << 2)];
                const float4 zp4 = *(const float4*)&s1[((rz1 + 1) * S1Y + ry1) * NX + (cxq << 2)];
                float4 Dv, Rv;
                const int idx = baseb + z * PLANE + y * NX + (cxq << 2);
                if constexpr (FIRST) {
                    Dv = ld4(Dm + idx);
                    Rv = ld4(Rm + idx);
                } else {
                    const uint4 pk = *(const uint4*)(dr + idx);
                    Dv = unpackD(pk);
                    Rv = unpackR(pk);
                }
                o = fkstep(m1, cv, xm, xp, ym4, yp4, zm4, zp4, Dv, Rv);
            }
            if (kk == 0) s2h0 = o; else s2h1 = o;
        }
    }
    __syncthreads();                                 // barrier 2: s1 reads done

    // ---- Publish staged s2 into the same storage (s2 layout) ----
    {
        const int ry2 = yi + 1;
        #pragma unroll
        for (int rz2 = 0; rz2 < S2Z; ++rz2)
            *(float4*)&s2b[(rz2 * S2Y + ry2) * NX + (xq << 2)] = s2i[rz2];
        #pragma unroll
        for (int kk = 0; kk < 2; ++kk) {
            const int i = tid + kk * 256;
            if (i < 12 * 32) {
                const int cxq = i & 31;
                const int r   = i >> 5;
                const int ry2h = (r < 6) ? 0 : 9;
                const int rz2h = (r < 6) ? r : r - 6;
                *(float4*)&s2b[(rz2h * S2Y + ry2h) * NX + (cxq << 2)] = (kk == 0) ? s2h0 : s2h1;
            }
        }
    }
    __syncthreads();                                 // barrier 3: s2 complete

    // ---- Phase 3: step-3 on the interior from s2; dr from registers;
    // z-rolled s2 planes; fp16 store normally, clipped f32 to `out` on the
    // item's last launch. ----
    {
        const int ry2 = yi + 1;
        const int y   = y0 + yi;
        float4 zmv = *(const float4*)&s2b[(0 * S2Y + ry2) * NX + (xq << 2)];
        float4 cv  = *(const float4*)&s2b[(1 * S2Y + ry2) * NX + (xq << 2)];
        #pragma unroll
        for (int k = 0; k < TZ; ++k) {
            const int rz2 = k + 1;
            const float4 zpv = *(const float4*)&s2b[((rz2 + 1) * S2Y + ry2) * NX + (xq << 2)];
            const float* rowc = &s2b[(rz2 * S2Y + ry2) * NX];
            const float xm = (xq > 0)  ? rowc[(xq << 2) - 1] : 0.0f;
            const float xp = (xq < 31) ? rowc[(xq << 2) + 4] : 0.0f;
            const float4 ym4 = *(const float4*)&s2b[(rz2 * S2Y + ry2 - 1) * NX + (xq << 2)];
            const float4 yp4 = *(const float4*)&s2b[(rz2 * S2Y + ry2 + 1) * NX + (xq << 2)];

            float4 o = fkstep(m2, cv, xm, xp, ym4, yp4, zmv, zpv,
                              unpackD(pr[k]), unpackR(pr[k]));
            const int idx = baseb + (z0 + k) * PLANE + y * NX + (xq << 2);
            if (last) {
                o.x = clip01(o.x); o.y = clip01(o.y);
                o.z = clip01(o.z); o.w = clip01(o.w);
                *(float4*)(out + idx) = o;
            } else {
                st4h(dsth + idx, o);
            }
            zmv = cv; cv = zpv;
        }
    }
}

extern "C" void kernel_launch(void* const* d_in, const int* in_sizes, int n_in,
                              void* d_out, int out_size, void* d_ws, size_t ws_size,
                              hipStream_t stream) {
    const float* u0  = (const float*)d_in[0];
    const float* Dm  = (const float*)d_in[1];
    const float* Rm  = (const float*)d_in[2];
    const int*   dtd = (const int*)d_in[3];
    float* out = (float*)d_out;
    // ws layout: [0,8M) fp16 buf0, [8M,16M) fp16 buf1, [16M,32M) packed DR.
    __half* hb0 = (__half*)d_ws;
    __half* hb1 = hb0 + TOTAL;
    uint32_t* dr = (uint32_t*)(hb1 + TOTAL);

    // Launch p advances steps 3p..3p+2 (inactive sub-steps masked to identity).
    // src: f32 u0 for p=0 else fp16 buf[(p-1)&1]; normal dst is fp16 buf[p&1];
    // an item's LAST launch redirects to f32 `out` (clipped) on-device.
    // d==0 items emit clip(u0) during launch 0.
    for (int p = 0; p < MAX_TRIPLES; ++p) {
        __half* dsth = (p & 1) ? hb1 : hb0;
        if (p == 0) {
            fk_triple<true><<<BLOCKS, 256, 0, stream>>>(
                u0, nullptr, dsth, out, u0, Dm, Rm, dr, dtd, p);
        } else {
            const __half* srch = ((p - 1) & 1) ? hb1 : hb0;
            fk_triple<false><<<BLOCKS, 256, 0, stream>>>(
                nullptr, srch, dsth, out, u0, Dm, Rm, dr, dtd, p);
        }
    }
}

// Round 10
// 242.168 us; speedup vs baseline: 1.0660x; 1.0660x over previous
//
#include <hip/hip_runtime.h>
#include <cstdint>

// Fisher-Kolmogorov explicit Euler, B=2, 128^3, up to 30 masked micro-steps
// (delta_t_days = randint(0,4) -> d <= 3 -> steps <= 30).
// Round-19: R16 structure scaled to TY=16 / 512 threads / 80 KB LDS.
//  Post-mortems: fp16 state (R18: 258) and LDS-staging (R14: 299) both
//  falsified byte-bound; occupancy/barrier/launch/XCD axes all null.
//  Per-step time invariant ~7.7us -> limiter is phase-1's serialized global
//  gather (~13 load-insts/interior cell at 3x region redundancy) with
//  partial cross-block overlap. This round cuts redundancy 3.0x -> 2.5x
//  (region 8x20 over interior 4x16) AND raises occupancy 12 -> 16 waves/CU
//  (2 blocks x 8 waves; LDS 80KB x 2 = 160KB = full pool), same verified
//  3-barrier register-staged chain, f32 state, bf16 dr, XCD z-slab swizzle.
//  Pre-commit: >=228 -> declare structural floor (~230) for this problem.

constexpr int NX = 128, NY = 128, NZ = 128;
constexpr int PLANE = NX * NY;            // 16384
constexpr int VOL   = NZ * PLANE;         // 2,097,152
constexpr int TOTAL = 2 * VOL;            // 4,194,304
constexpr float DT  = 0.1f;               // MICRO_DT
constexpr int MAX_TRIPLES = 10;           // 30 steps / 3

constexpr int TY = 16, TZ = 4;            // block interior tile (x full 128)
constexpr int S1Z = TZ + 4, S1Y = TY + 4; // step-1 region: 8 z x 20 y (80 KB)
constexpr int S2Z = TZ + 2, S2Y = TY + 2; // step-2 region: 6 z x 18 y (aliased)
constexpr int BLOCKS  = 2 * (NZ / TZ) * (NY / TY);  // 2*32*8 = 512
constexpr int THREADS = 512;              // 16 rows x 32 f4-lanes

__device__ __forceinline__ float4 ld4(const float* p) { return *(const float4*)p; }

__device__ __forceinline__ uint32_t f2bf(float f) {
    uint32_t u = __float_as_uint(f);
    u += 0x7fffu + ((u >> 16) & 1u);      // round-to-nearest-even
    return u >> 16;
}
__device__ __forceinline__ float bf_lo(uint32_t p) { return __uint_as_float(p << 16); }
__device__ __forceinline__ float bf_hi(uint32_t p) { return __uint_as_float(p & 0xffff0000u); }
__device__ __forceinline__ float clip01(float v) { return fminf(fmaxf(v, 0.0f), 1.0f); }

__device__ __forceinline__ float4 fkstep(float dt, float4 c, float xm, float xp,
                                         float4 ym, float4 yp,
                                         float4 zm, float4 zp,
                                         float4 Dv, float4 Rv) {
    float4 o;
    o.x = fmaf(dt, fmaf(Dv.x, (xm + c.y) + (ym.x + yp.x) + (zm.x + zp.x) - 6.0f * c.x,
                        Rv.x * c.x * (1.0f - c.x)), c.x);
    o.y = fmaf(dt, fmaf(Dv.y, (c.x + c.z) + (ym.y + yp.y) + (zm.y + zp.y) - 6.0f * c.y,
                        Rv.y * c.y * (1.0f - c.y)), c.y);
    o.z = fmaf(dt, fmaf(Dv.z, (c.y + c.w) + (ym.z + yp.z) + (zm.z + zp.z) - 6.0f * c.z,
                        Rv.z * c.z * (1.0f - c.z)), c.z);
    o.w = fmaf(dt, fmaf(Dv.w, (c.z + xp) + (ym.w + yp.w) + (zm.w + zp.w) - 6.0f * c.w,
                        Rv.w * c.w * (1.0f - c.w)), c.w);
    return o;
}

__device__ __forceinline__ float4 unpackD(uint4 p) {
    return make_float4(bf_lo(p.x), bf_lo(p.y), bf_lo(p.z), bf_lo(p.w));
}
__device__ __forceinline__ float4 unpackR(uint4 p) {
    return make_float4(bf_hi(p.x), bf_hi(p.y), bf_hi(p.z), bf_hi(p.w));
}

__global__ __launch_bounds__(THREADS, 4)   // 4 waves/EU = 16 waves/CU = 2 blocks
void fk_triple(const float* __restrict__ src, float* __restrict__ dst0,
               float* __restrict__ out, const float* __restrict__ u0,
               const float* __restrict__ Dm, const float* __restrict__ Rm,
               uint32_t* __restrict__ dr, const int* __restrict__ dtd, int p)
{
    // ---- XCD-slab swizzle: bid%8 selects a contiguous z-slab ----
    const int bid  = blockIdx.x;
    const int slab = bid & 7;                        // XCD key 0..7
    const int rest = bid >> 3;                       // 0..63
    const int b    = rest >> 5;                      // batch item
    const int zw   = (rest >> 3) & 3;                // z tile within slab
    const int yt   = rest & 7;                       // y tile 0..7
    const int zb   = slab * 4 + zw;                  // z tile 0..31

    int d = dtd[b]; d = d < 0 ? 0 : (d > 3 ? 3 : d); // randint(0,4) is excl-upper
    const int steps = d * 10;
    const int g0 = 3 * p;                            // first global step of launch

    const int z0 = zb * TZ, y0 = yt * TY;
    const int tid = threadIdx.x;
    const int xq  = tid & 31;                        // float4 lane within row
    const int yi  = tid >> 5;                        // 0..15
    const int baseb = b << 21;
    const float4 zero = make_float4(0.f, 0.f, 0.f, 0.f);

    if (g0 >= steps) {
        // d==0 items never get a step write: emit clip(u0) once, in launch 0.
        if (steps == 0 && p == 0) {
            #pragma unroll
            for (int k = 0; k < TZ; ++k) {
                const int idx = baseb + (z0 + k) * PLANE + (y0 + yi) * NX + (xq << 2);
                const float4 v = ld4(u0 + idx);
                float4 o;
                o.x = clip01(v.x); o.y = clip01(v.y);
                o.z = clip01(v.z); o.w = clip01(v.w);
                *(float4*)(out + idx) = o;
            }
        }
        return;                                      // block-uniform exit
    }
    const bool first = (p == 0);
    const bool last  = (steps - g0 <= 3);
    float* __restrict__ dst = last ? out : dst0;
    const float m1 = (g0 + 1 < steps) ? DT : 0.0f;   // sub-step masks (g0 active)
    const float m2 = (g0 + 2 < steps) ? DT : 0.0f;   // fmaf(0,du,u)==u exactly

    __shared__ float s1[S1Z * S1Y * NX];             // 80 KiB; s2 aliases this
    float* const s2b = s1;                           // s2 layout: [S2Z][S2Y][NX]

    uint4 pr[TZ];                                    // packed (D,rho) bf16, interior

    // ---- Phase 1 pass 0: step-1 on interior-y columns of s1 (rows yi+2),
    // z-rolled over all 8 s1 planes (z0-2 .. z0+5). Publishes interior dr. ----
    {
        const int y = y0 + yi;                       // in-domain by construction
        const int colbase = baseb + y * NX + (xq << 2);
        const bool has_ym = (y > 0), has_yp = (y < NY - 1);
        const bool has_l = (xq > 0), has_r = (xq < 31);
        const int zlo = z0 - 2;

        float4 um = ((unsigned)(zlo - 1) < (unsigned)NZ) ? ld4(src + colbase + (zlo - 1) * PLANE) : zero;
        float4 uc = ((unsigned)zlo < (unsigned)NZ) ? ld4(src + colbase + zlo * PLANE) : zero;
        #pragma unroll
        for (int rz = 0; rz < S1Z; ++rz) {
            const int z = zlo + rz;
            const int idx = colbase + z * PLANE;
            const float4 un = ((unsigned)(z + 1) < (unsigned)NZ) ? ld4(src + idx + PLANE) : zero;
            float4 o = zero;
            if ((unsigned)z < (unsigned)NZ) {
                const float4 ym4 = has_ym ? ld4(src + idx - NX) : zero;
                const float4 yp4 = has_yp ? ld4(src + idx + NX) : zero;
                const float xm = has_l ? src[idx - 1] : 0.0f;
                const float xp = has_r ? src[idx + 4] : 0.0f;
                float4 Dv, Rv;
                if (first) {
                    Dv = ld4(Dm + idx);
                    Rv = ld4(Rm + idx);
                    if (rz >= 2 && rz < 2 + TZ) {    // interior z: publish + keep
                        uint4 pk;
                        pk.x = f2bf(Dv.x) | (f2bf(Rv.x) << 16);
                        pk.y = f2bf(Dv.y) | (f2bf(Rv.y) << 16);
                        pk.z = f2bf(Dv.z) | (f2bf(Rv.z) << 16);
                        pk.w = f2bf(Dv.w) | (f2bf(Rv.w) << 16);
                        *(uint4*)(dr + idx) = pk;
                        pr[rz - 2] = pk;
                    }
                } else {
                    const uint4 pk = *(const uint4*)(dr + idx);
                    Dv = unpackD(pk);
                    Rv = unpackR(pk);
                    if (rz >= 2 && rz < 2 + TZ) pr[rz - 2] = pk;
                }
                o = fkstep(DT, uc, xm, xp, ym4, yp4, um, un, Dv, Rv);
            }
            *(float4*)&s1[(rz * S1Y + (yi + 2)) * NX + (xq << 2)] = o;
            um = uc; uc = un;
        }
    }

    // ---- Phase 1 pass 1: step-1 on the 4 y-halo rows {0,1,18,19} x 8 planes
    // = 1024 row-tasks, 2 iterations over 512 threads. ----
    #pragma unroll
    for (int kk = 0; kk < 2; ++kk) {
        const int i   = tid + kk * 512;              // 0..1023
        const int cxq = i & 31;
        const int r   = i >> 5;                      // 0..31
        const int rr  = r >> 3;                      // 0..3
        const int rz  = r & 7;
        const int ry  = (rr < 2) ? rr : rr + 16;     // 0,1,18,19
        const int y = y0 - 2 + ry;
        const int z = z0 - 2 + rz;
        float4 o = zero;                             // out-of-domain -> 0
        if ((unsigned)y < (unsigned)NY && (unsigned)z < (unsigned)NZ) {
            const int idx = baseb + z * PLANE + y * NX + (cxq << 2);
            const float4 c  = ld4(src + idx);
            const float xm  = (cxq > 0)  ? src[idx - 1] : 0.0f;
            const float xp  = (cxq < 31) ? src[idx + 4] : 0.0f;
            const float4 ym4 = (y > 0)      ? ld4(src + idx - NX)    : zero;
            const float4 yp4 = (y < NY - 1) ? ld4(src + idx + NX)    : zero;
            const float4 zm4 = (z > 0)      ? ld4(src + idx - PLANE) : zero;
            const float4 zp4 = (z < NZ - 1) ? ld4(src + idx + PLANE) : zero;
            float4 Dv, Rv;
            if (first) {
                Dv = ld4(Dm + idx);
                Rv = ld4(Rm + idx);
            } else {
                const uint4 pk = *(const uint4*)(dr + idx);
                Dv = unpackD(pk);
                Rv = unpackR(pk);
            }
            o = fkstep(DT, c, xm, xp, ym4, yp4, zm4, zp4, Dv, Rv);
        }
        *(float4*)&s1[(rz * S1Y + ry) * NX + (cxq << 2)] = o;
    }
    __syncthreads();                                 // barrier 1: s1 complete

    // ---- Phase 2 (register-staged): step-2 from s1 into registers ----
    float4 s2i[S2Z];                                 // interior rows, ry2 = yi+1
    {
        const int ry1 = yi + 2;                      // this cell's s1 row
        float4 zmv = *(const float4*)&s1[(0 * S1Y + ry1) * NX + (xq << 2)];
        float4 cv  = *(const float4*)&s1[(1 * S1Y + ry1) * NX + (xq << 2)];
        #pragma unroll
        for (int rz2 = 0; rz2 < S2Z; ++rz2) {
            const int rz1 = rz2 + 1;
            const float4 zpv = *(const float4*)&s1[((rz1 + 1) * S1Y + ry1) * NX + (xq << 2)];
            const int z = z0 - 1 + rz2;
            float4 o = zero;
            if ((unsigned)z < (unsigned)NZ) {
                const float* rowc = &s1[(rz1 * S1Y + ry1) * NX];
                const float xm = (xq > 0)  ? rowc[(xq << 2) - 1] : 0.0f;
                const float xp = (xq < 31) ? rowc[(xq << 2) + 4] : 0.0f;
                const float4 ym4 = *(const float4*)&s1[(rz1 * S1Y + ry1 - 1) * NX + (xq << 2)];
                const float4 yp4 = *(const float4*)&s1[(rz1 * S1Y + ry1 + 1) * NX + (xq << 2)];
                float4 Dv, Rv;
                if (rz2 >= 1 && rz2 < 1 + TZ) {      // interior z: from registers
                    Dv = unpackD(pr[rz2 - 1]);
                    Rv = unpackR(pr[rz2 - 1]);
                } else {                             // z halo planes
                    const int idx = baseb + z * PLANE + (y0 + yi) * NX + (xq << 2);
                    if (first) {
                        Dv = ld4(Dm + idx);
                        Rv = ld4(Rm + idx);
                    } else {
                        const uint4 pk = *(const uint4*)(dr + idx);
                        Dv = unpackD(pk);
                        Rv = unpackR(pk);
                    }
                }
                o = fkstep(m1, cv, xm, xp, ym4, yp4, zmv, zpv, Dv, Rv);
            }
            s2i[rz2] = o;
            zmv = cv; cv = zpv;
        }
    }

    // y-halo rows of s2: rows {0,17} x 6 planes = 384 row-tasks (<512),
    // staged in one register each.
    float4 s2h0 = zero;
    if (tid < 12 * 32) {
        const int cxq = tid & 31;
        const int r   = tid >> 5;                    // 0..11
        const int ry2 = (r < 6) ? 0 : S2Y - 1;       // 0 or 17
        const int rz2 = (r < 6) ? r : r - 6;
        const int y = y0 - 1 + ry2;
        const int z = z0 - 1 + rz2;
        if ((unsigned)y < (unsigned)NY && (unsigned)z < (unsigned)NZ) {
            const int rz1 = rz2 + 1, ry1 = ry2 + 1;
            const float* rowc = &s1[(rz1 * S1Y + ry1) * NX];
            const float4 cv = *(const float4*)&rowc[cxq << 2];
            const float xm = (cxq > 0)  ? rowc[(cxq << 2) - 1] : 0.0f;
            const float xp = (cxq < 31) ? rowc[(cxq << 2) + 4] : 0.0f;
            const float4 ym4 = *(const float4*)&s1[(rz1 * S1Y + ry1 - 1) * NX + (cxq << 2)];
            const float4 yp4 = *(const float4*)&s1[(rz1 * S1Y + ry1 + 1) * NX + (cxq << 2)];
            const float4 zm4 = *(const float4*)&s1[((rz1 - 1) * S1Y + ry1) * NX + (cxq << 2)];
            const float4 zp4 = *(const float4*)&s1[((rz1 + 1) * S1Y + ry1) * NX + (cxq << 2)];
            float4 Dv, Rv;
            const int idx = baseb + z * PLANE + y * NX + (cxq << 2);
            if (first) {
                Dv = ld4(Dm + idx);
                Rv = ld4(Rm + idx);
            } else {
                const uint4 pk = *(const uint4*)(dr + idx);
                Dv = unpackD(pk);
                Rv = unpackR(pk);
            }
            s2h0 = fkstep(m1, cv, xm, xp, ym4, yp4, zm4, zp4, Dv, Rv);
        }
    }
    __syncthreads();                                 // barrier 2: s1 reads done

    // ---- Publish staged s2 into the same storage (s2 layout) ----
    {
        const int ry2 = yi + 1;
        #pragma unroll
        for (int rz2 = 0; rz2 < S2Z; ++rz2)
            *(float4*)&s2b[(rz2 * S2Y + ry2) * NX + (xq << 2)] = s2i[rz2];
        if (tid < 12 * 32) {
            const int cxq = tid & 31;
            const int r   = tid >> 5;
            const int ry2h = (r < 6) ? 0 : S2Y - 1;
            const int rz2h = (r < 6) ? r : r - 6;
            *(float4*)&s2b[(rz2h * S2Y + ry2h) * NX + (cxq << 2)] = s2h0;
        }
    }
    __syncthreads();                                 // barrier 3: s2 complete

    // ---- Phase 3: step-3 on the interior from s2; dr from registers;
    // z-rolled s2 planes; clip + redirect to `out` on the item's last launch. ----
    {
        const int ry2 = yi + 1;
        const int y   = y0 + yi;
        float4 zmv = *(const float4*)&s2b[(0 * S2Y + ry2) * NX + (xq << 2)];
        float4 cv  = *(const float4*)&s2b[(1 * S2Y + ry2) * NX + (xq << 2)];
        #pragma unroll
        for (int k = 0; k < TZ; ++k) {
            const int rz2 = k + 1;
            const float4 zpv = *(const float4*)&s2b[((rz2 + 1) * S2Y + ry2) * NX + (xq << 2)];
            const float* rowc = &s2b[(rz2 * S2Y + ry2) * NX];
            const float xm = (xq > 0)  ? rowc[(xq << 2) - 1] : 0.0f;
            const float xp = (xq < 31) ? rowc[(xq << 2) + 4] : 0.0f;
            const float4 ym4 = *(const float4*)&s2b[(rz2 * S2Y + ry2 - 1) * NX + (xq << 2)];
            const float4 yp4 = *(const float4*)&s2b[(rz2 * S2Y + ry2 + 1) * NX + (xq << 2)];

            float4 o = fkstep(m2, cv, xm, xp, ym4, yp4, zmv, zpv,
                              unpackD(pr[k]), unpackR(pr[k]));
            if (last) {
                o.x = clip01(o.x); o.y = clip01(o.y);
                o.z = clip01(o.z); o.w = clip01(o.w);
            }
            const int idx = baseb + (z0 + k) * PLANE + y * NX + (xq << 2);
            *(float4*)(dst + idx) = o;
            zmv = cv; cv = zpv;
        }
    }
}

extern "C" void kernel_launch(void* const* d_in, const int* in_sizes, int n_in,
                              void* d_out, int out_size, void* d_ws, size_t ws_size,
                              hipStream_t stream) {
    const float* u0  = (const float*)d_in[0];
    const float* Dm  = (const float*)d_in[1];
    const float* Rm  = (const float*)d_in[2];
    const int*   dtd = (const int*)d_in[3];
    float* out = (float*)d_out;
    float* ws  = (float*)d_ws;
    // ws layout: [0,16M) buf0, [16M,32M) buf1, [32M,48M) packed DR (ws=256MB).
    float* buf[2] = { ws, ws + TOTAL };
    uint32_t* dr = (uint32_t*)(ws + 2 * TOTAL);

    // Launch p advances steps 3p..3p+2 (inactive sub-steps masked to identity).
    // src: u0 for p=0 else buf[(p-1)&1]; normal dst alternates buf[p&1]; an
    // item's LAST launch redirects to `out` (clipped) on-device. d==0 items
    // emit clip(u0) during launch 0.
    for (int p = 0; p < MAX_TRIPLES; ++p) {
        const float* src = (p == 0) ? u0 : buf[(p - 1) & 1];
        fk_triple<<<BLOCKS, THREADS, 0, stream>>>(src, buf[p & 1], out, u0,
                                                  Dm, Rm, dr, dtd, p);
    }
}

// Round 11
// 228.510 us; speedup vs baseline: 1.1297x; 1.0598x over previous
//
#include <hip/hip_runtime.h>
#include <cstdint>

// Fisher-Kolmogorov explicit Euler, B=2, 128^3, up to 30 masked micro-steps
// (delta_t_days = randint(0,4) -> d <= 3 -> steps <= 30).
// Round-20 = R16 verbatim (best verified: 230.5us). Session-final revert.
//  Complete bracket (11 experiments): fusion 2/3-step, occupancy 8/12/16
//  waves/CU, barriers 2/3/16, byte cuts (LDS-staging 299, fp16-state 258 --
//  both NEGATIVE), XCD z-slab swizzle (-1.7%, kept), launch count 10/20,
//  cooperative single-launch (grid.sync ~33us/ea -> 1064, dead), halo
//  redundancy 3.0x/2.5x (242, negative). Per-step cost pinned ~7.7us in a
//  latency/serialization regime (2.3-2.9 TB/s TCC, VALUBusy 9-20%).
//  This structure: 3 steps/launch, 10 launches; TY=8 x TZ=4 tile; 48KB LDS
//  (s2 register-staged then aliased into s1's storage); 3 barriers;
//  packed bf16 (D,rho) in ws; per-item masking via dt=0 identity steps;
//  last-launch clip+redirect to `out` on-device.

constexpr int NX = 128, NY = 128, NZ = 128;
constexpr int PLANE = NX * NY;            // 16384
constexpr int VOL   = NZ * PLANE;         // 2,097,152
constexpr int TOTAL = 2 * VOL;            // 4,194,304
constexpr float DT  = 0.1f;               // MICRO_DT
constexpr int MAX_TRIPLES = 10;           // 30 steps / 3

constexpr int TY = 8, TZ = 4;             // block interior tile (x full 128)
constexpr int S1Z = TZ + 4, S1Y = TY + 4; // step-1 region: 8 z x 12 y (48 KB)
constexpr int S2Z = TZ + 2, S2Y = TY + 2; // step-2 region: 6 z x 10 y (aliased)
constexpr int BLOCKS = 2 * (NZ / TZ) * (NY / TY);  // 2*32*16 = 1024

__device__ __forceinline__ float4 ld4(const float* p) { return *(const float4*)p; }

__device__ __forceinline__ uint32_t f2bf(float f) {
    uint32_t u = __float_as_uint(f);
    u += 0x7fffu + ((u >> 16) & 1u);      // round-to-nearest-even
    return u >> 16;
}
__device__ __forceinline__ float bf_lo(uint32_t p) { return __uint_as_float(p << 16); }
__device__ __forceinline__ float bf_hi(uint32_t p) { return __uint_as_float(p & 0xffff0000u); }
__device__ __forceinline__ float clip01(float v) { return fminf(fmaxf(v, 0.0f), 1.0f); }

__device__ __forceinline__ float4 fkstep(float dt, float4 c, float xm, float xp,
                                         float4 ym, float4 yp,
                                         float4 zm, float4 zp,
                                         float4 Dv, float4 Rv) {
    float4 o;
    o.x = fmaf(dt, fmaf(Dv.x, (xm + c.y) + (ym.x + yp.x) + (zm.x + zp.x) - 6.0f * c.x,
                        Rv.x * c.x * (1.0f - c.x)), c.x);
    o.y = fmaf(dt, fmaf(Dv.y, (c.x + c.z) + (ym.y + yp.y) + (zm.y + zp.y) - 6.0f * c.y,
                        Rv.y * c.y * (1.0f - c.y)), c.y);
    o.z = fmaf(dt, fmaf(Dv.z, (c.y + c.w) + (ym.z + yp.z) + (zm.z + zp.z) - 6.0f * c.z,
                        Rv.z * c.z * (1.0f - c.z)), c.z);
    o.w = fmaf(dt, fmaf(Dv.w, (c.z + xp) + (ym.w + yp.w) + (zm.w + zp.w) - 6.0f * c.w,
                        Rv.w * c.w * (1.0f - c.w)), c.w);
    return o;
}

__device__ __forceinline__ float4 unpackD(uint4 p) {
    return make_float4(bf_lo(p.x), bf_lo(p.y), bf_lo(p.z), bf_lo(p.w));
}
__device__ __forceinline__ float4 unpackR(uint4 p) {
    return make_float4(bf_hi(p.x), bf_hi(p.y), bf_hi(p.z), bf_hi(p.w));
}

__global__ __launch_bounds__(256, 3)
void fk_triple(const float* __restrict__ src, float* __restrict__ dst0,
               float* __restrict__ out, const float* __restrict__ u0,
               const float* __restrict__ Dm, const float* __restrict__ Rm,
               uint32_t* __restrict__ dr, const int* __restrict__ dtd, int p)
{
    // ---- XCD-slab swizzle: bid%8 selects a contiguous z-slab ----
    const int bid  = blockIdx.x;
    const int slab = bid & 7;                        // XCD key 0..7
    const int rest = bid >> 3;                       // 0..127
    const int b    = rest >> 6;                      // batch item
    const int zw   = (rest >> 4) & 3;                // z tile within slab
    const int yt   = rest & 15;                      // y tile
    const int zb   = slab * 4 + zw;                  // z tile 0..31

    int d = dtd[b]; d = d < 0 ? 0 : (d > 3 ? 3 : d); // randint(0,4) is excl-upper
    const int steps = d * 10;
    const int g0 = 3 * p;                            // first global step of launch

    const int z0 = zb * TZ, y0 = yt * TY;
    const int tid = threadIdx.x;
    const int xq  = tid & 31;                        // float4 lane within row
    const int yi  = tid >> 5;                        // 0..7
    const int baseb = b << 21;
    const float4 zero = make_float4(0.f, 0.f, 0.f, 0.f);

    if (g0 >= steps) {
        // d==0 items never get a step write: emit clip(u0) once, in launch 0.
        if (steps == 0 && p == 0) {
            #pragma unroll
            for (int k = 0; k < TZ; ++k) {
                const int idx = baseb + (z0 + k) * PLANE + (y0 + yi) * NX + (xq << 2);
                const float4 v = ld4(u0 + idx);
                float4 o;
                o.x = clip01(v.x); o.y = clip01(v.y);
                o.z = clip01(v.z); o.w = clip01(v.w);
                *(float4*)(out + idx) = o;
            }
        }
        return;                                      // block-uniform exit
    }
    const bool first = (p == 0);
    const bool last  = (steps - g0 <= 3);
    float* __restrict__ dst = last ? out : dst0;
    const float m1 = (g0 + 1 < steps) ? DT : 0.0f;   // sub-step masks (g0 active)
    const float m2 = (g0 + 2 < steps) ? DT : 0.0f;   // fmaf(0,du,u)==u exactly

    __shared__ float s1[S1Z * S1Y * NX];             // 48 KiB; s2 aliases this
    float* const s2b = s1;                           // s2 layout: [S2Z][S2Y][NX]

    uint4 pr[TZ];                                    // packed (D,rho) bf16, interior

    // ---- Phase 1 pass 0: step-1 on interior-y columns of s1, z-rolled over
    // all 8 s1 planes (z0-2 .. z0+5). Captures/publishes interior dr. ----
    {
        const int y = y0 + yi;                       // in-domain by construction
        const int colbase = baseb + y * NX + (xq << 2);
        const bool has_ym = (y > 0), has_yp = (y < NY - 1);
        const bool has_l = (xq > 0), has_r = (xq < 31);
        const int zlo = z0 - 2;

        float4 um = ((unsigned)(zlo - 1) < (unsigned)NZ) ? ld4(src + colbase + (zlo - 1) * PLANE) : zero;
        float4 uc = ((unsigned)zlo < (unsigned)NZ) ? ld4(src + colbase + zlo * PLANE) : zero;
        #pragma unroll
        for (int rz = 0; rz < S1Z; ++rz) {
            const int z = zlo + rz;
            const int idx = colbase + z * PLANE;
            const float4 un = ((unsigned)(z + 1) < (unsigned)NZ) ? ld4(src + idx + PLANE) : zero;
            float4 o = zero;
            if ((unsigned)z < (unsigned)NZ) {
                const float4 ym4 = has_ym ? ld4(src + idx - NX) : zero;
                const float4 yp4 = has_yp ? ld4(src + idx + NX) : zero;
                const float xm = has_l ? src[idx - 1] : 0.0f;
                const float xp = has_r ? src[idx + 4] : 0.0f;
                float4 Dv, Rv;
                if (first) {
                    Dv = ld4(Dm + idx);
                    Rv = ld4(Rm + idx);
                    if (rz >= 2 && rz < 2 + TZ) {    // interior z: publish + keep
                        uint4 pk;
                        pk.x = f2bf(Dv.x) | (f2bf(Rv.x) << 16);
                        pk.y = f2bf(Dv.y) | (f2bf(Rv.y) << 16);
                        pk.z = f2bf(Dv.z) | (f2bf(Rv.z) << 16);
                        pk.w = f2bf(Dv.w) | (f2bf(Rv.w) << 16);
                        *(uint4*)(dr + idx) = pk;
                        pr[rz - 2] = pk;
                    }
                } else {
                    const uint4 pk = *(const uint4*)(dr + idx);
                    Dv = unpackD(pk);
                    Rv = unpackR(pk);
                    if (rz >= 2 && rz < 2 + TZ) pr[rz - 2] = pk;
                }
                o = fkstep(DT, uc, xm, xp, ym4, yp4, um, un, Dv, Rv);
            }
            *(float4*)&s1[(rz * S1Y + (yi + 2)) * NX + (xq << 2)] = o;
            um = uc; uc = un;
        }
    }

    // ---- Phase 1 pass 1: step-1 on the 4 y-halo rows x 8 planes (32 row-
    // tasks, flat over all threads, 4 iterations). ----
    for (int i = tid; i < 32 * 32; i += 256) {
        const int cxq = i & 31;
        const int r   = i >> 5;                      // 0..31
        const int rr  = r >> 3;                      // 0..3
        const int rz  = r & 7;
        const int ry  = (rr < 2) ? rr : rr + 8;      // 0,1,10,11
        const int y = y0 - 2 + ry;
        const int z = z0 - 2 + rz;
        float4 o = zero;                             // out-of-domain -> 0
        if ((unsigned)y < (unsigned)NY && (unsigned)z < (unsigned)NZ) {
            const int idx = baseb + z * PLANE + y * NX + (cxq << 2);
            const float4 c  = ld4(src + idx);
            const float xm  = (cxq > 0)  ? src[idx - 1] : 0.0f;
            const float xp  = (cxq < 31) ? src[idx + 4] : 0.0f;
            const float4 ym4 = (y > 0)      ? ld4(src + idx - NX)    : zero;
            const float4 yp4 = (y < NY - 1) ? ld4(src + idx + NX)    : zero;
            const float4 zm4 = (z > 0)      ? ld4(src + idx - PLANE) : zero;
            const float4 zp4 = (z < NZ - 1) ? ld4(src + idx + PLANE) : zero;
            float4 Dv, Rv;
            if (first) {
                Dv = ld4(Dm + idx);
                Rv = ld4(Rm + idx);
            } else {
                const uint4 pk = *(const uint4*)(dr + idx);
                Dv = unpackD(pk);
                Rv = unpackR(pk);
            }
            o = fkstep(DT, c, xm, xp, ym4, yp4, zm4, zp4, Dv, Rv);
        }
        *(float4*)&s1[(rz * S1Y + ry) * NX + (cxq << 2)] = o;
    }
    __syncthreads();                                 // barrier 1: s1 complete

    // ---- Phase 2 (register-staged): step-2 from s1 into registers ----
    float4 s2i[S2Z];                                 // interior rows, ry2 = yi+1
    {
        const int ry1 = yi + 2;                      // this cell's s1 row
        float4 zmv = *(const float4*)&s1[(0 * S1Y + ry1) * NX + (xq << 2)];
        float4 cv  = *(const float4*)&s1[(1 * S1Y + ry1) * NX + (xq << 2)];
        #pragma unroll
        for (int rz2 = 0; rz2 < S2Z; ++rz2) {
            const int rz1 = rz2 + 1;
            const float4 zpv = *(const float4*)&s1[((rz1 + 1) * S1Y + ry1) * NX + (xq << 2)];
            const int z = z0 - 1 + rz2;
            float4 o = zero;
            if ((unsigned)z < (unsigned)NZ) {
                const float* rowc = &s1[(rz1 * S1Y + ry1) * NX];
                const float xm = (xq > 0)  ? rowc[(xq << 2) - 1] : 0.0f;
                const float xp = (xq < 31) ? rowc[(xq << 2) + 4] : 0.0f;
                const float4 ym4 = *(const float4*)&s1[(rz1 * S1Y + ry1 - 1) * NX + (xq << 2)];
                const float4 yp4 = *(const float4*)&s1[(rz1 * S1Y + ry1 + 1) * NX + (xq << 2)];
                float4 Dv, Rv;
                if (rz2 >= 1 && rz2 < 1 + TZ) {      // interior z: from registers
                    Dv = unpackD(pr[rz2 - 1]);
                    Rv = unpackR(pr[rz2 - 1]);
                } else {                             // z halo planes
                    const int idx = baseb + z * PLANE + (y0 + yi) * NX + (xq << 2);
                    if (first) {
                        Dv = ld4(Dm + idx);
                        Rv = ld4(Rm + idx);
                    } else {
                        const uint4 pk = *(const uint4*)(dr + idx);
                        Dv = unpackD(pk);
                        Rv = unpackR(pk);
                    }
                }
                o = fkstep(m1, cv, xm, xp, ym4, yp4, zmv, zpv, Dv, Rv);
            }
            s2i[rz2] = o;
            zmv = cv; cv = zpv;
        }
    }

    // y-halo rows of s2: 12 row-tasks x 32 f4 = 384 tasks, staged in regs.
    float4 s2h0 = zero, s2h1 = zero;
    #pragma unroll
    for (int kk = 0; kk < 2; ++kk) {
        const int i = tid + kk * 256;
        if (i < 12 * 32) {
            const int cxq = i & 31;
            const int r   = i >> 5;                  // 0..11
            const int ry2 = (r < 6) ? 0 : 9;
            const int rz2 = (r < 6) ? r : r - 6;
            const int y = y0 - 1 + ry2;
            const int z = z0 - 1 + rz2;
            float4 o = zero;
            if ((unsigned)y < (unsigned)NY && (unsigned)z < (unsigned)NZ) {
                const int rz1 = rz2 + 1, ry1 = ry2 + 1;
                const float* rowc = &s1[(rz1 * S1Y + ry1) * NX];
                const float4 cv = *(const float4*)&rowc[cxq << 2];
                const float xm = (cxq > 0)  ? rowc[(cxq << 2) - 1] : 0.0f;
                const float xp = (cxq < 31) ? rowc[(cxq << 2) + 4] : 0.0f;
                const float4 ym4 = *(const float4*)&s1[(rz1 * S1Y + ry1 - 1) * NX + (cxq << 2)];
                const float4 yp4 = *(const float4*)&s1[(rz1 * S1Y + ry1 + 1) * NX + (cxq << 2)];
                const float4 zm4 = *(const float4*)&s1[((rz1 - 1) * S1Y + ry1) * NX + (cxq << 2)];
                const float4 zp4 = *(const float4*)&s1[((rz1 + 1) * S1Y + ry1) * NX + (cxq << 2)];
                float4 Dv, Rv;
                const int idx = baseb + z * PLANE + y * NX + (cxq << 2);
                if (first) {
                    Dv = ld4(Dm + idx);
                    Rv = ld4(Rm + idx);
                } else {
                    const uint4 pk = *(const uint4*)(dr + idx);
                    Dv = unpackD(pk);
                    Rv = unpackR(pk);
                }
                o = fkstep(m1, cv, xm, xp, ym4, yp4, zm4, zp4, Dv, Rv);
            }
            if (kk == 0) s2h0 = o; else s2h1 = o;
        }
    }
    __syncthreads();                                 // barrier 2: s1 reads done

    // ---- Publish staged s2 into the same storage (s2 layout) ----
    {
        const int ry2 = yi + 1;
        #pragma unroll
        for (int rz2 = 0; rz2 < S2Z; ++rz2)
            *(float4*)&s2b[(rz2 * S2Y + ry2) * NX + (xq << 2)] = s2i[rz2];
        #pragma unroll
        for (int kk = 0; kk < 2; ++kk) {
            const int i = tid + kk * 256;
            if (i < 12 * 32) {
                const int cxq = i & 31;
                const int r   = i >> 5;
                const int ry2h = (r < 6) ? 0 : 9;
                const int rz2h = (r < 6) ? r : r - 6;
                *(float4*)&s2b[(rz2h * S2Y + ry2h) * NX + (cxq << 2)] = (kk == 0) ? s2h0 : s2h1;
            }
        }
    }
    __syncthreads();                                 // barrier 3: s2 complete

    // ---- Phase 3: step-3 on the interior from s2; dr from registers;
    // z-rolled s2 planes; clip + redirect to `out` on the item's last launch. ----
    {
        const int ry2 = yi + 1;
        const int y   = y0 + yi;
        float4 zmv = *(const float4*)&s2b[(0 * S2Y + ry2) * NX + (xq << 2)];
        float4 cv  = *(const float4*)&s2b[(1 * S2Y + ry2) * NX + (xq << 2)];
        #pragma unroll
        for (int k = 0; k < TZ; ++k) {
            const int rz2 = k + 1;
            const float4 zpv = *(const float4*)&s2b[((rz2 + 1) * S2Y + ry2) * NX + (xq << 2)];
            const float* rowc = &s2b[(rz2 * S2Y + ry2) * NX];
            const float xm = (xq > 0)  ? rowc[(xq << 2) - 1] : 0.0f;
            const float xp = (xq < 31) ? rowc[(xq << 2) + 4] : 0.0f;
            const float4 ym4 = *(const float4*)&s2b[(rz2 * S2Y + ry2 - 1) * NX + (xq << 2)];
            const float4 yp4 = *(const float4*)&s2b[(rz2 * S2Y + ry2 + 1) * NX + (xq << 2)];

            float4 o = fkstep(m2, cv, xm, xp, ym4, yp4, zmv, zpv,
                              unpackD(pr[k]), unpackR(pr[k]));
            if (last) {
                o.x = clip01(o.x); o.y = clip01(o.y);
                o.z = clip01(o.z); o.w = clip01(o.w);
            }
            const int idx = baseb + (z0 + k) * PLANE + y * NX + (xq << 2);
            *(float4*)(dst + idx) = o;
            zmv = cv; cv = zpv;
        }
    }
}

extern "C" void kernel_launch(void* const* d_in, const int* in_sizes, int n_in,
                              void* d_out, int out_size, void* d_ws, size_t ws_size,
                              hipStream_t stream) {
    const float* u0  = (const float*)d_in[0];
    const float* Dm  = (const float*)d_in[1];
    const float* Rm  = (const float*)d_in[2];
    const int*   dtd = (const int*)d_in[3];
    float* out = (float*)d_out;
    float* ws  = (float*)d_ws;
    // ws layout: [0,16M) buf0, [16M,32M) buf1, [32M,48M) packed DR (ws=256MB).
    float* buf[2] = { ws, ws + TOTAL };
    uint32_t* dr = (uint32_t*)(ws + 2 * TOTAL);

    // Launch p advances steps 3p..3p+2 (inactive sub-steps masked to identity).
    // src: u0 for p=0 else buf[(p-1)&1]; normal dst alternates buf[p&1]; an
    // item's LAST launch redirects to `out` (clipped) on-device. d==0 items
    // emit clip(u0) during launch 0.
    for (int p = 0; p < MAX_TRIPLES; ++p) {
        const float* src = (p == 0) ? u0 : buf[(p - 1) & 1];
        fk_triple<<<BLOCKS, 256, 0, stream>>>(src, buf[p & 1], out, u0,
                                              Dm, Rm, dr, dtd, p);
    }
}